// Round 10
// baseline (397.544 us; speedup 1.0000x reference)
//
#include <hip/hip_runtime.h>
#include <hip/hip_bf16.h>

typedef __attribute__((ext_vector_type(8)))  __bf16         bf16x8;
typedef __attribute__((ext_vector_type(4)))  float          f32x4;
typedef __attribute__((ext_vector_type(8)))  unsigned short u16x8;

#define LOG2E 1.44269504088896340736f

#if __has_builtin(__builtin_amdgcn_exp2f)
#define EXP2F(x) __builtin_amdgcn_exp2f(x)
#else
#define EXP2F(x) __builtin_exp2f(x)
#endif

__device__ __forceinline__ unsigned short f2b(float f) {
  union { __bf16 h; unsigned short s; } o; o.h = (__bf16)f; return o.s;
}

// ---------------- kernel 1: h = x@W fp32 (VALU); hT bf16, s1', s2' ----------
// UNCHANGED from green round 8.
__global__ __launch_bounds__(256) void k_prep(
    const float* __restrict__ x, const float* __restrict__ W,
    const float* __restrict__ a1, const float* __restrict__ a2,
    const float* __restrict__ ab,
    unsigned short* __restrict__ hT, float* __restrict__ s1p,
    float* __restrict__ s2p) {
  __shared__ __align__(16) float Ws[64 * 128];
  __shared__ __align__(16) float Xs[16 * 128];
  const int t = threadIdx.x;
  const int rb = blockIdx.x * 16;
  const int r  = t >> 4;
  const int fg = t & 15;

  {
    int off = t * 8;
    *(f32x4*)(Xs + off)     = *(const f32x4*)(x + (long)rb * 128 + off);
    *(f32x4*)(Xs + off + 4) = *(const f32x4*)(x + (long)rb * 128 + off + 4);
  }

  float acc[8];
#pragma unroll
  for (int j = 0; j < 8; ++j) acc[j] = 0.f;

  for (int half = 0; half < 2; ++half) {
    __syncthreads();
#pragma unroll
    for (int c = 0; c < 8; ++c) {
      int off = c * 1024 + t * 4;
      *(f32x4*)(Ws + off) = *(const f32x4*)(W + half * 8192 + off);
    }
    __syncthreads();
    for (int k = 0; k < 64; ++k) {
      float xv = Xs[r * 128 + half * 64 + k];
      f32x4 w0 = *(const f32x4*)(Ws + k * 128 + fg * 8);
      f32x4 w1 = *(const f32x4*)(Ws + k * 128 + fg * 8 + 4);
#pragma unroll
      for (int j = 0; j < 4; ++j) {
        acc[j]     += xv * w0[j];
        acc[4 + j] += xv * w1[j];
      }
    }
  }

  float p1 = 0.f, p2 = 0.f;
#pragma unroll
  for (int j = 0; j < 8; ++j) {
    p1 += acc[j] * a1[fg * 8 + j];
    p2 += acc[j] * a2[fg * 8 + j];
  }
#pragma unroll
  for (int mask = 1; mask <= 8; mask <<= 1) {
    p1 += __shfl_xor(p1, mask, 64);
    p2 += __shfl_xor(p2, mask, 64);
  }
  if (fg == 0) {
    s1p[rb + r] = LOG2E * (p1 + ab[0]);
    s2p[rb + r] = LOG2E * p2;
  }
#pragma unroll
  for (int j = 0; j < 8; ++j)
    hT[(long)(fg * 8 + j) * 8192 + rb + r] = f2b(acc[j]);
}

// ---------------- kernel 2 v3: split-M, full-K, direct out ------------------
// grid 512 = row-blocks of 16; 512 thr (8 waves), 2 blocks/CU. Same sync
// skeleton as green r8 (identical Bs staging map, identical load placement:
// adj/s2 issued before barrier-1, hT after barrier-1). No ws partials, no
// k_comb — the r9 cross-kernel hazard class is structurally eliminated.
__global__ __launch_bounds__(512, 4) void k_attn(
    const float* __restrict__ adj, const unsigned short* __restrict__ hT,
    const float* __restrict__ s1p, const float* __restrict__ s2p,
    float* __restrict__ out) {
  __shared__ __align__(16) unsigned short Bs[128 * 128];  // hT k-tile, XOR-swizzled
  __shared__ __align__(16) unsigned short As[16 * 136];   // w tile, +8 pad/row
  __shared__ float dens[16];

  const int t = threadIdx.x;
  const int i0 = blockIdx.x * 16;
  const int lane = t & 63;
  const int wv = t >> 6;          // 0..7
  const int m    = lane & 15;
  const int quad = lane >> 4;     // 0..3
  const int f0 = wv * 16;         // wave's 16-feature tile

  const int wr = t >> 5;          // w-phase row 0..15
  const int wc = t & 31;          // w-phase 4-col chunk 0..31
  const int sf    = t >> 4;       // staging row-within-round 0..31
  const int sslot = t & 15;       // staging LDS slot

  const float s1v = s1p[i0 + wr];
  const float* adjp = adj + (long)(i0 + wr) * 8192 + wc * 4;
  const float* s2pp = s2p + wc * 4;

  f32x4 acc;
#pragma unroll
  for (int p = 0; p < 4; ++p) acc[p] = 0.f;
  float den = 0.f;

  // prologue: iter-0 adj/s2 + hT staging regs (r8 pattern)
  f32x4 ar = __builtin_nontemporal_load((const f32x4*)(adjp));
  f32x4 cs = *(const f32x4*)(s2pp);
  u16x8 stg[4];
#pragma unroll
  for (int rr = 0; rr < 4; ++rr) {
    int f = rr * 32 + sf;
    int cg = sslot ^ (f & 7);
    stg[rr] = *(const u16x8*)(hT + (long)f * 8192 + cg * 8);
  }

  for (int it = 0; it < 64; ++it) {
    // ---- staged hT regs -> Bs (global chunk cg sits at slot sslot) ----
#pragma unroll
    for (int rr = 0; rr < 4; ++rr) {
      int f = rr * 32 + sf;
      *(u16x8*)(Bs + f * 128 + sslot * 8) = stg[rr];
    }
    // ---- prefetch next adj/s2 (before barrier-1, as in green r8) ----
    const int itn = (it + 1) & 63;
    f32x4 nr = __builtin_nontemporal_load((const f32x4*)(adjp + (long)itn * 128));
    f32x4 ns = *(const f32x4*)(s2pp + itn * 128);

    // ---- w = adj * exp2(leaky(t')) for this thread's 4 columns ----
    {
      ushort4 w;
      float dloc = 0.f;
      float tp0 = s1v + cs[0];
      float tp1 = s1v + cs[1];
      float tp2 = s1v + cs[2];
      float tp3 = s1v + cs[3];
      float w0 = ar[0] * EXP2F(fmaxf(tp0, 0.2f * tp0));
      float w1 = ar[1] * EXP2F(fmaxf(tp1, 0.2f * tp1));
      float w2 = ar[2] * EXP2F(fmaxf(tp2, 0.2f * tp2));
      float w3 = ar[3] * EXP2F(fmaxf(tp3, 0.2f * tp3));
      dloc = (w0 + w1) + (w2 + w3);
      w.x = f2b(w0); w.y = f2b(w1); w.z = f2b(w2); w.w = f2b(w3);
      den += dloc;
      *(ushort4*)(As + wr * 136 + wc * 4) = w;
    }

    __syncthreads();   // barrier-1: As/Bs visible to all waves

    // ---- prefetch next hT tile (after barrier-1, as in green r8) ----
    if (it < 63) {
      const unsigned short* hTi = hT + (long)(it + 1) * 128;
#pragma unroll
      for (int rr = 0; rr < 4; ++rr) {
        int f = rr * 32 + sf;
        int cg = sslot ^ (f & 7);
        stg[rr] = *(const u16x8*)(hTi + (long)f * 8192 + cg * 8);
      }
    }

    // ---- 4x mfma_f32_16x16x32_bf16 (1 feature tile x 4 K-steps) ----
#pragma unroll
    for (int ks = 0; ks < 4; ++ks) {
      bf16x8 af = *(const bf16x8*)(As + m * 136 + ks * 32 + quad * 8);
      int slotx = (ks * 4 + quad) ^ ((f0 + m) & 7);
      bf16x8 bv = *(const bf16x8*)(Bs + (f0 + m) * 128 + slotx * 8);
      acc = __builtin_amdgcn_mfma_f32_16x16x32_bf16(af, bv, acc, 0, 0, 0);
    }
    __syncthreads();   // barrier-2: reads done before next iter's stores

    ar = nr; cs = ns;
  }

  // ---- full-row denominator: reduce over wc (lane low5), share via LDS ----
  den += __shfl_xor(den, 1, 64);
  den += __shfl_xor(den, 2, 64);
  den += __shfl_xor(den, 4, 64);
  den += __shfl_xor(den, 8, 64);
  den += __shfl_xor(den, 16, 64);
  if (wc == 0) dens[wr] = den;
  __syncthreads();

  // ---- divide + fp32 store. C layout (16x16): col=m, row=quad*4+p ----
#pragma unroll
  for (int p = 0; p < 4; ++p) {
    int row = quad * 4 + p;
    float d = dens[row];
    float inv = (d != 0.f) ? (1.f / d) : 0.f;
    out[(long)(i0 + row) * 128 + f0 + m] = acc[p] * inv;
  }
}

extern "C" void kernel_launch(void* const* d_in, const int* in_sizes, int n_in,
                              void* d_out, int out_size, void* d_ws, size_t ws_size,
                              hipStream_t stream) {
  int ix = 0, iadj = 1, iw = 2, ia1 = 3, ia2 = 4, iab = 5;
  {
    int f128[2] = {-1, -1};
    int tx = -1, tadj = -1, tw = -1, tab = -1, n128 = 0;
    for (int i = 0; i < n_in; ++i) {
      int s = in_sizes[i];
      if (s == 67108864) tadj = i;
      else if (s == 1048576) tx = i;
      else if (s == 16384) tw = i;
      else if (s == 128 && n128 < 2) f128[n128++] = i;
      else if (s == 1) tab = i;
    }
    if (tx >= 0 && tadj >= 0 && tw >= 0 && tab >= 0 && n128 == 2) {
      ix = tx; iadj = tadj; iw = tw; ia1 = f128[0]; ia2 = f128[1]; iab = tab;
    }
  }
  const float* x   = (const float*)d_in[ix];
  const float* adj = (const float*)d_in[iadj];
  const float* W   = (const float*)d_in[iw];
  const float* a1  = (const float*)d_in[ia1];
  const float* a2  = (const float*)d_in[ia2];
  const float* ab  = (const float*)d_in[iab];

  char* ws = (char*)d_ws;
  unsigned short* hT = (unsigned short*)(ws);           // 2 MB  bf16 h^T [128][8192]
  float* s1p = (float*)(ws + 2097152);                  // 32 KB
  float* s2p = (float*)(ws + 2097152 + 32768);          // 32 KB

  k_prep<<<dim3(512), dim3(256), 0, stream>>>(x, W, a1, a2, ab, hT, s1p, s2p);
  k_attn<<<dim3(512), dim3(512), 0, stream>>>(adj, hT, s1p, s2p, (float*)d_out);
}